// Round 3
// baseline (66.954 us; speedup 1.0000x reference)
//
#include <hip/hip_runtime.h>

// OneHotEmbedding == row gather: out[i,:] = embeddings[inputs[i],:]
// N=16384, VOCAB=32000, EMB=128 (float32).
// One 16B vector per thread: row = t>>5, col = t&31.
// 32 consecutive lanes share one index -> broadcast load; emb row read and
// out write are fully coalesced 16 B/lane.
// R2: nontemporal hints via native clang vector type (HIP float4 is a struct
// and is rejected by __builtin_nontemporal_*).

#define N_ROWS 16384
#define EMB 128
#define EMB4 (EMB / 4)  // 32 16B-vectors per row

typedef float vfloat4 __attribute__((ext_vector_type(4)));

__global__ __launch_bounds__(256) void OneHotEmbedding_87522843561070_kernel(
    const int* __restrict__ idx,
    const vfloat4* __restrict__ emb,
    vfloat4* __restrict__ out) {
    int t = blockIdx.x * blockDim.x + threadIdx.x;  // 0 .. N_ROWS*EMB4-1
    int row = t >> 5;
    int col = t & 31;
    int e = idx[row];
    vfloat4 v = __builtin_nontemporal_load(&emb[(long)e * EMB4 + col]);
    __builtin_nontemporal_store(v, &out[t]);
}

extern "C" void kernel_launch(void* const* d_in, const int* in_sizes, int n_in,
                              void* d_out, int out_size, void* d_ws, size_t ws_size,
                              hipStream_t stream) {
    const int* idx = (const int*)d_in[0];
    const vfloat4* emb = (const vfloat4*)d_in[1];
    vfloat4* out = (vfloat4*)d_out;

    const int total = N_ROWS * EMB4;       // 524288 vectors
    const int block = 256;
    const int grid = total / block;        // 2048 blocks

    OneHotEmbedding_87522843561070_kernel<<<grid, block, 0, stream>>>(idx, emb, out);
}